// Round 1
// 122.521 us; speedup vs baseline: 1.0214x; 1.0214x over previous
//
#include <hip/hip_runtime.h>
#include <hip/hip_fp16.h>

// Problem constants (from reference).
#define N_GENOMES 30000
#define N_GENES   240000
#define N_SAMPLES 128
#define N_SEQS    80000
#define CAP       32   // max genes per seq (Poisson mean 3; P(overflow) ~ 3e-17)

#define SCATTER_BLOCKS  ((N_GENES + 255) / 256)        // 938
#define COMPRESS_BLOCKS ((N_GENOMES * 32) / 256)       // 3750 (exact)

// Native vector types for __builtin_nontemporal_load/store.
typedef float        f32x4 __attribute__((ext_vector_type(4)));
typedef unsigned int u32x4 __attribute__((ext_vector_type(4)));

#define LOG2E 1.4426950408889634f

#if __has_builtin(__builtin_amdgcn_exp2f)
#define EXP2F(x) __builtin_amdgcn_exp2f(x)
#else
#define EXP2F(x) exp2f(x)
#endif

// ---------------------------------------------------------------------------
// Fused prep kernel.
// Blocks [0, SCATTER_BLOCKS): bucket-scatter genes by seq id with PACKED 4B
//   records: genome (15 bits) | pos quantized to 17 bits. Slots 0..3 go to a
//   DENSE bucket0 [N_SEQS][4] (16B rows -> accum chunk-0 reads are fully
//   dense, 8x fewer cache lines than the old 128B-row layout); slots 4..31
//   spill to bucketOv [N_SEQS][28]. Neither is pre-zeroed; accum masks dead
//   slots by count.
// Blocks [SCATTER_BLOCKS, ...): compress A/B to fp16 with +1 and log2(e)
//   folded in, but re-laid-out XCD-SHARDED: AB16T[qg][genome][qw] where
//   qg = quad>>2 (8 groups of 4 quads), qw = quad&3. Each qg slice is
//   30000*64B = 1.92 MB. Accum maps blockIdx%8 -> qg, so under round-robin
//   block->XCD dispatch each XCD's 4 MiB L2 holds its entire slice and the
//   123 MB of random gathers become L2 hits instead of L3 random access.
// ---------------------------------------------------------------------------
__global__ __launch_bounds__(256) void prep_kernel(
    const float* __restrict__ A,
    const float* __restrict__ B,
    const float* __restrict__ pos,
    const int*   __restrict__ genome_idx,
    const int*   __restrict__ seq_idx,
    int*          __restrict__ cnt,      // N_SEQS, zeroed
    unsigned int* __restrict__ bucket0,  // N_SEQS*4 packed records (uninit)
    unsigned int* __restrict__ bucketOv, // N_SEQS*28 packed records (uninit)
    float4*       __restrict__ AB16)     // 8 x 30000 x 4 float4, qg-major
{
    int b = blockIdx.x;
    if (b < SCATTER_BLOCKS) {
        int gene = b * 256 + threadIdx.x;
        if (gene >= N_GENES) return;
        int   s = seq_idx[gene];
        int   g = genome_idx[gene];
        float p = pos[gene];
        unsigned int q   = (unsigned int)(p * 131072.0f);   // exact mul, trunc
        unsigned int rec = (unsigned int)g | (q << 15);
        int slot = atomicAdd(&cnt[s], 1);
        if (slot < 4)        bucket0[s * 4 + slot] = rec;
        else if (slot < CAP) bucketOv[s * 28 + (slot - 4)] = rec;
    } else {
        int idx = (b - SCATTER_BLOCKS) * 256 + threadIdx.x; // genome*32+quad
        f32x4 a  = __builtin_nontemporal_load((const f32x4*)A + idx);
        f32x4 bb = __builtin_nontemporal_load((const f32x4*)B + idx);
        __half2 h[4];
        h[0] = __floats2half2_rn((a.x + 1.0f) * LOG2E, (a.y + 1.0f) * LOG2E);
        h[1] = __floats2half2_rn((a.z + 1.0f) * LOG2E, (a.w + 1.0f) * LOG2E);
        h[2] = __floats2half2_rn(bb.x * LOG2E, bb.y * LOG2E);
        h[3] = __floats2half2_rn(bb.z * LOG2E, bb.w * LOG2E);
        int genome = idx >> 5;
        int quad   = idx & 31;
        int qg = quad >> 2, qw = quad & 3;
        // qg-major sharded layout; cached store (accum re-reads it).
        AB16[((size_t)qg * N_GENOMES + genome) * 4 + qw] =
            *reinterpret_cast<float4*>(h);
    }
}

// ---------------------------------------------------------------------------
// Accum kernel, XCD-sharded by sample-quad-group.
// Block b: qg = b%8 (-> XCD b%8 under round-robin dispatch), covers 64 seqs
// x 4 quads (qw 0..3). Each XCD only gathers from its own 1.92 MB AB16T
// slice -> L2-resident after first touch. Bucket chunk-0 rows are dense 16B
// -> a wave's 16 seqs read 256B contiguous.
// Trade-off (watched): out store per thread is float4 at seq*512B + quad*16B,
// i.e. 64B-contiguous per (seq,qg) instead of the old 512B bursts. Accepted
// because the gather was the bigger cost; revert sharding if this regresses.
// Every out element is written (n==0 -> zeros), so no out memset needed.
// ---------------------------------------------------------------------------
__global__ __launch_bounds__(256) void accum_kernel(
    const float4*       __restrict__ AB16,
    const int*          __restrict__ cnt,
    const unsigned int* __restrict__ bucket0,
    const unsigned int* __restrict__ bucketOv,
    float*              __restrict__ out)
{
    int b   = blockIdx.x;
    int qg  = b & 7;
    int tid = threadIdx.x;
    int seq = (b >> 3) * 64 + (tid >> 2);   // grid exact: 1250*64 = 80000
    int qw  = tid & 3;

    // Dense 16B chunk-0 row; issued immediately, independent of cnt.
    u32x4 r4 = reinterpret_cast<const u32x4*>(bucket0)[seq];
    int   n  = cnt[seq];                    // issued in parallel with r4
    if (n > CAP) n = CAP;

    // This XCD's slice base, offset by this thread's qw.
    const float4* T = AB16 + (size_t)qg * N_GENOMES * 4 + qw;

    float4 acc = make_float4(0.f, 0.f, 0.f, 0.f);

    // Chunk 0 (covers n<=4: the vast majority of non-empty seqs).
    {
        unsigned int r[4] = { r4.x, r4.y, r4.z, r4.w };
        float4 raw[4];
        #pragma unroll
        for (int j = 0; j < 4; ++j) {
            unsigned int g = (j < n) ? (r[j] & 0x7fffu) : 0u;  // dead -> row 0 (hot)
            raw[j] = T[(size_t)g * 4];
        }
        #pragma unroll
        for (int j = 0; j < 4; ++j) {
            float p = (float)(r[j] >> 15) * (1.0f / 131072.0f);
            const __half2* hp = reinterpret_cast<const __half2*>(&raw[j]);
            float2 a01 = __half22float2(hp[0]);
            float2 a23 = __half22float2(hp[1]);
            float2 b01 = __half22float2(hp[2]);
            float2 b23 = __half22float2(hp[3]);
            if (j < n) {                       // (a+1) and log2e folded into AB16
                acc.x += EXP2F(a01.x - p * b01.x);
                acc.y += EXP2F(a01.y - p * b01.y);
                acc.z += EXP2F(a23.x - p * b23.x);
                acc.w += EXP2F(a23.y - p * b23.y);
            }
        }
    }

    // Rare tail: n > 4 (P ~ 18%), chunks of 4 from the spill array.
    if (n > 4) {
        const u32x4* bkv =
            reinterpret_cast<const u32x4*>(bucketOv + (size_t)seq * 28); // 112B: 16B-aligned
        for (int i0 = 4; i0 < n; i0 += 4) {
            u32x4 t4 = bkv[(i0 - 4) >> 2];
            unsigned int r[4] = { t4.x, t4.y, t4.z, t4.w };
            float4 raw[4];
            #pragma unroll
            for (int j = 0; j < 4; ++j) {
                unsigned int g = (i0 + j < n) ? (r[j] & 0x7fffu) : 0u;
                raw[j] = T[(size_t)g * 4];
            }
            #pragma unroll
            for (int j = 0; j < 4; ++j) {
                float p = (float)(r[j] >> 15) * (1.0f / 131072.0f);
                const __half2* hp = reinterpret_cast<const __half2*>(&raw[j]);
                float2 a01 = __half22float2(hp[0]);
                float2 a23 = __half22float2(hp[1]);
                float2 b01 = __half22float2(hp[2]);
                float2 b23 = __half22float2(hp[3]);
                if (i0 + j < n) {
                    acc.x += EXP2F(a01.x - p * b01.x);
                    acc.y += EXP2F(a01.y - p * b01.y);
                    acc.z += EXP2F(a23.x - p * b23.x);
                    acc.w += EXP2F(a23.y - p * b23.y);
                }
            }
        }
    }

    // Out is written once and never re-read -> nontemporal.
    int quad = (qg << 2) + qw;
    f32x4 o = { acc.x, acc.y, acc.z, acc.w };
    __builtin_nontemporal_store(o, (f32x4*)out + (size_t)seq * 32 + quad);
}

extern "C" void kernel_launch(void* const* d_in, const int* in_sizes, int n_in,
                              void* d_out, int out_size, void* d_ws, size_t ws_size,
                              hipStream_t stream) {
    const float* A    = (const float*)d_in[0];
    const float* B    = (const float*)d_in[1];
    const float* pos  = (const float*)d_in[2];
    const int*   gidx = (const int*)d_in[3];
    const int*   sidx = (const int*)d_in[4];
    float*       out  = (float*)d_out;

    // Workspace layout (256 MiB available, ~25.9 MB used):
    //   [0, 15,360,000)              AB16T: 8 x 30000 x 4 float4, qg-major
    //   [15,360,000, 15,680,000)     cnt: N_SEQS ints
    //   [15,680,000, 16,960,000)     bucket0: N_SEQS*4 uints (dense 16B rows)
    //   [16,960,000, 25,920,000)     bucketOv: N_SEQS*28 uints (spill)
    char*         ws       = (char*)d_ws;
    float4*       AB16     = (float4*)ws;
    int*          cnt      = (int*)(ws + (size_t)N_GENOMES * 32 * 16);
    unsigned int* bucket0  = (unsigned int*)(cnt + N_SEQS);
    unsigned int* bucketOv = bucket0 + (size_t)N_SEQS * 4;

    // Zero ONLY cnt (320 KB): bucket dead slots are masked by count in accum.
    hipMemsetAsync(cnt, 0, N_SEQS * sizeof(int), stream);

    prep_kernel<<<SCATTER_BLOCKS + COMPRESS_BLOCKS, 256, 0, stream>>>(
        A, B, pos, gidx, sidx, cnt, bucket0, bucketOv, AB16);

    // 8 qg-shards x 1250 seq-blocks; blockIdx%8 = qg -> XCD under
    // round-robin dispatch (bijective: 10000 % 8 == 0).
    accum_kernel<<<(N_SEQS / 64) * 8, 256, 0, stream>>>(
        AB16, cnt, bucket0, bucketOv, out);
}